// Round 3
// baseline (97.181 us; speedup 1.0000x reference)
//
#include <hip/hip_runtime.h>

// B=4096, Z=128, DEG=16, E=2048. out[b,i,j]=1 except out[b,src[e],dst[e]]=beta[b,e].
// src[e]=e/16 -> row i owns edges [16i,16i+16).
//
// LDS-free design: each wave owns 2 output rows. Per iteration (batch pair):
//   1) issue 2 x-loads + 2 unconditional ones-float4 stores (pure streaming,
//      fill-kernel-like: no input dependence on the store data)
//   2) s_waitcnt vmcnt(4) -> previous iteration's ones-stores are complete
//   3) scatter previous iteration's beta dword (overwrites a ones position;
//      same wave wrote those ones -> ordering guaranteed by the executed wait)
//   4) compute this iteration's tiny MLP into registers
// Beta dwords hit L2-resident lines (just written) -> merged, ~no extra HBM.

#define ZONES 128
#define NB    64   // batches per block

__device__ __forceinline__ float fast_tanh(float v) {
    float e = __expf(2.0f * v);
    return 1.0f - 2.0f * __builtin_amdgcn_rcpf(e + 1.0f);
}
__device__ __forceinline__ float fast_sigmoid(float v) {
    return __builtin_amdgcn_rcpf(1.0f + __expf(-v));
}

__global__ __launch_bounds__(256) void fused_edge_mlp(
    const float* __restrict__ x,
    const int*   __restrict__ dst,
    const float* __restrict__ W1,
    const float* __restrict__ b1,
    const float* __restrict__ W2,
    const float* __restrict__ b2,
    const float* __restrict__ W3,
    const float* __restrict__ b3,
    float* __restrict__ out)
{
    const int tid  = threadIdx.x;
    const int w    = tid >> 6;            // wave 0..3 (owns rows 2w, 2w+1)
    const int lane = tid & 63;
    const int rg   = blockIdx.x;          // row group: rows rg*8 .. rg*8+7
    const int b0   = blockIdx.y * NB;

    // beta mapping: lane -> (batch half, edge within wave's 2 rows)
    const int boff = lane >> 5;           // 0/1: which batch of the pair
    const int slot = lane & 31;           // 2 rows x 16 edges
    const int srow = rg * 8 + 2 * w + (slot >> 4);   // output row
    const int e    = srow * 16 + (slot & 15);        // global edge id
    const int dcol = dst[e];                         // output col

    // ones mapping: lane -> (row 2w + lane/32, float4-col lane%32), same rows
    const size_t obase = (size_t)((rg * 8 + 2 * w + boff) * 32 + slot);

    // hoist this lane's edge weights (reused for all NB batches)
    float w1[8], b1v[4], w2[16], b2v[4], w3v[4];
    *(float4*)&w1[0]  = ((const float4*)(W1 + e * 8))[0];
    *(float4*)&w1[4]  = ((const float4*)(W1 + e * 8))[1];
    *(float4*)&b1v[0] = ((const float4*)(b1 + e * 4))[0];
    *(float4*)&w2[0]  = ((const float4*)(W2 + e * 16))[0];
    *(float4*)&w2[4]  = ((const float4*)(W2 + e * 16))[1];
    *(float4*)&w2[8]  = ((const float4*)(W2 + e * 16))[2];
    *(float4*)&w2[12] = ((const float4*)(W2 + e * 16))[3];
    *(float4*)&b2v[0] = ((const float4*)(b2 + e * 4))[0];
    *(float4*)&w3v[0] = ((const float4*)(W3 + e * 4))[0];
    const float b3s = b3[e];

    float4* out4 = (float4*)out;
    const float4 ones4 = make_float4(1.f, 1.f, 1.f, 1.f);

    float  pbeta = 0.f;
    size_t paddr = 0;

    #pragma unroll 4
    for (int it = 0; it < NB / 2; ++it) {
        const int bA = b0 + 2 * it;
        const int bm = bA + boff;         // this lane's beta batch

        asm volatile("" ::: "memory");
        const float xs = x[bm * ZONES + srow];
        const float xd = x[bm * ZONES + dcol];
        out4[(size_t)bA * 4096 + obase]       = ones4;
        out4[(size_t)(bA + 1) * 4096 + obase] = ones4;
        asm volatile("" ::: "memory");

        // drain everything older than this iteration's 4 vmem ops:
        // previous iteration's ones-stores + beta store are now complete.
        asm volatile("s_waitcnt vmcnt(4)" ::: "memory");
        if (it > 0) out[paddr] = pbeta;

        // tiny MLP 2->4->4->1
        float h1[4];
        #pragma unroll
        for (int o = 0; o < 4; ++o)
            h1[o] = fast_tanh(fmaf(xs, w1[o], fmaf(xd, w1[4 + o], b1v[o])));

        float h2[4];
        #pragma unroll
        for (int o = 0; o < 4; ++o) {
            float z = b2v[o];
            #pragma unroll
            for (int k = 0; k < 4; ++k)
                z = fmaf(h1[k], w2[k * 4 + o], z);
            h2[o] = fast_tanh(z);
        }

        float z = b3s;
        #pragma unroll
        for (int o = 0; o < 4; ++o)
            z = fmaf(h2[o], w3v[o], z);

        pbeta = fast_sigmoid(z);
        paddr = (size_t)bm * (ZONES * ZONES) + srow * ZONES + dcol;
    }

    asm volatile("s_waitcnt vmcnt(0)" ::: "memory");
    out[paddr] = pbeta;
}

extern "C" void kernel_launch(void* const* d_in, const int* in_sizes, int n_in,
                              void* d_out, int out_size, void* d_ws, size_t ws_size,
                              hipStream_t stream) {
    // setup_inputs order: x, dtPt, src, dst, W1, b1, W2, b2, W3, b3
    const float* x   = (const float*)d_in[0];
    const int*   dst = (const int*)  d_in[3];
    const float* W1  = (const float*)d_in[4];
    const float* b1  = (const float*)d_in[5];
    const float* W2  = (const float*)d_in[6];
    const float* b2  = (const float*)d_in[7];
    const float* W3  = (const float*)d_in[8];
    const float* b3  = (const float*)d_in[9];
    float* out = (float*)d_out;

    const int B = in_sizes[0] / ZONES;     // 4096
    dim3 grid(ZONES / 8, B / NB);          // (16, 64) = 1024 blocks
    fused_edge_mlp<<<grid, 256, 0, stream>>>(x, dst, W1, b1, W2, b2, W3, b3, out);
}

// Round 5
// 53.879 us; speedup vs baseline: 1.8037x; 1.8037x over previous
//
#include <hip/hip_runtime.h>

// B=4096, Z=128, DEG=16, E=2048. out[b,i,j]=1 except out[b,src[e],dst[e]]=beta[b,e].
// src[e]=e/16 -> row i owns edges [16i,16i+16).
//
// Barrier-free design: each WAVE owns 2 output rows x 2 batches per iteration.
// That is exactly 64 betas = 1 tiny-MLP per lane. The wave scatters its betas
// into a PRIVATE 2KB LDS region (ones-initialized once; beta positions are
// batch-invariant so only the 64 beta slots are ever rewritten), then reads
// the region back as float4 and streams it to global with nontemporal stores.
// Producer set == consumer set at wave granularity -> NO __syncthreads anywhere;
// same-wave LDS ordering is handled by the compiler's lgkmcnt insertion.

#define ZONES 128
#define NB    32   // batches per block

typedef float f32x4 __attribute__((ext_vector_type(4)));

__device__ __forceinline__ float fast_tanh(float v) {
    float e = __expf(2.0f * v);
    return 1.0f - 2.0f * __builtin_amdgcn_rcpf(e + 1.0f);
}
__device__ __forceinline__ float fast_sigmoid(float v) {
    return __builtin_amdgcn_rcpf(1.0f + __expf(-v));
}

__global__ __launch_bounds__(256) void fused_edge_mlp(
    const float* __restrict__ x,
    const int*   __restrict__ dst,
    const float* __restrict__ W1,
    const float* __restrict__ b1,
    const float* __restrict__ W2,
    const float* __restrict__ b2,
    const float* __restrict__ W3,
    const float* __restrict__ b3,
    float* __restrict__ out)
{
    // per-wave private region: [batch-half][2 rows][128 cols] = 2 KB, 8 KB/block
    __shared__ float buf[4][2][2][ZONES];

    const int tid  = threadIdx.x;
    const int w    = tid >> 6;            // wave id: owns rows 2w, 2w+1 of group
    const int lane = tid & 63;
    const int rg   = blockIdx.x;          // row group: rows rg*8 .. rg*8+7
    const int b0   = blockIdx.y * NB;

    const int half = lane >> 5;           // 0/1: which batch of the pair
    const int slot = lane & 31;           // 2 rows x 16 edges
    const int row  = slot >> 4;           // row within wave's pair
    const int srow = rg * 8 + 2 * w + row;           // output row
    const int e    = srow * 16 + (slot & 15);        // global edge id
    const int dcol = dst[e];                         // output col

    // hoist this lane's edge weights (reused for all NB batches)
    float w1[8], b1v[4], w2[16], b2v[4], w3v[4];
    *(float4*)&w1[0]  = ((const float4*)(W1 + e * 8))[0];
    *(float4*)&w1[4]  = ((const float4*)(W1 + e * 8))[1];
    *(float4*)&b1v[0] = ((const float4*)(b1 + e * 4))[0];
    *(float4*)&w2[0]  = ((const float4*)(W2 + e * 16))[0];
    *(float4*)&w2[4]  = ((const float4*)(W2 + e * 16))[1];
    *(float4*)&w2[8]  = ((const float4*)(W2 + e * 16))[2];
    *(float4*)&w2[12] = ((const float4*)(W2 + e * 16))[3];
    *(float4*)&b2v[0] = ((const float4*)(b2 + e * 4))[0];
    *(float4*)&w3v[0] = ((const float4*)(W3 + e * 4))[0];
    const float b3s = b3[e];

    // init this wave's region to ones ONCE (128 float4, 2 per lane).
    f32x4* reg4 = (f32x4*)buf[w];
    const f32x4 ones4 = {1.f, 1.f, 1.f, 1.f};
    reg4[lane]      = ones4;
    reg4[lane + 64] = ones4;

    f32x4* out4 = (f32x4*)out;
    // lane's fixed output float4 slot within one batch image (rows 2w/2w+1)
    const size_t obase = (size_t)(rg * 8 + 2 * w) * 32 + lane;

    #pragma unroll 2
    for (int it = 0; it < NB / 2; ++it) {
        const int bA = b0 + 2 * it;
        const int bm = bA + half;         // this lane's beta batch

        const float xs = x[bm * ZONES + srow];
        const float xd = x[bm * ZONES + dcol];

        // tiny MLP 2->4->4->1
        float h1[4];
        #pragma unroll
        for (int o = 0; o < 4; ++o)
            h1[o] = fast_tanh(fmaf(xs, w1[o], fmaf(xd, w1[4 + o], b1v[o])));

        float h2[4];
        #pragma unroll
        for (int o = 0; o < 4; ++o) {
            float z = b2v[o];
            #pragma unroll
            for (int k = 0; k < 4; ++k)
                z = fmaf(h1[k], w2[k * 4 + o], z);
            h2[o] = fast_tanh(z);
        }

        float z = b3s;
        #pragma unroll
        for (int o = 0; o < 4; ++o)
            z = fmaf(h2[o], w3v[o], z);
        const float beta = fast_sigmoid(z);

        // scatter into the wave-private region (16 distinct cols per row)
        buf[w][half][row][dcol] = beta;

        // read back both batches' images (same wave wrote them; in-order DS
        // + compiler lgkmcnt give RAW ordering without any barrier)
        const f32x4 v0 = reg4[lane];         // batch bA   (half 0 region)
        const f32x4 v1 = reg4[lane + 64];    // batch bA+1 (half 1 region)

        __builtin_nontemporal_store(v0, &out4[(size_t)bA * 4096 + obase]);
        __builtin_nontemporal_store(v1, &out4[(size_t)(bA + 1) * 4096 + obase]);
    }
}

extern "C" void kernel_launch(void* const* d_in, const int* in_sizes, int n_in,
                              void* d_out, int out_size, void* d_ws, size_t ws_size,
                              hipStream_t stream) {
    // setup_inputs order: x, dtPt, src, dst, W1, b1, W2, b2, W3, b3
    const float* x   = (const float*)d_in[0];
    const int*   dst = (const int*)  d_in[3];
    const float* W1  = (const float*)d_in[4];
    const float* b1  = (const float*)d_in[5];
    const float* W2  = (const float*)d_in[6];
    const float* b2  = (const float*)d_in[7];
    const float* W3  = (const float*)d_in[8];
    const float* b3  = (const float*)d_in[9];
    float* out = (float*)d_out;

    const int B = in_sizes[0] / ZONES;     // 4096
    dim3 grid(ZONES / 8, B / NB);          // (16, 128) = 2048 blocks
    fused_edge_mlp<<<grid, 256, 0, stream>>>(x, dst, W1, b1, W2, b2, W3, b3, out);
}

// Round 6
// 53.171 us; speedup vs baseline: 1.8277x; 1.0133x over previous
//
#include <hip/hip_runtime.h>

// B=4096, Z=128, DEG=16, E=2048. out[b,i,j]=1 except out[b,src[e],dst[e]]=beta[b,e].
// src[e]=e/16 -> row i owns edges [16i,16i+16).
//
// Structure (R2 ping-pong, best measured) + two changes:
//  1) x staged in LDS once per block (coalesced prologue) -> main loop has ZERO
//     global reads: pure compute->store stream, emulating the 7 TB/s fill.
//     NB=64 -> 1024 blocks, 40 KB LDS -> exactly 4 blocks/CU, no tail.
//  2) MLP in packed f32 (f32x2 -> v_pk_fma_f32) with Padé(5,6) tanh sharing
//     one v_rcp per tanh pair. |z| <= ~4.5 reachable -> Padé err < 4e-4.

#define ZONES 128
#define NB    64   // batches per block

typedef float f32x2 __attribute__((ext_vector_type(2)));
typedef float f32x4 __attribute__((ext_vector_type(4)));

__device__ __forceinline__ f32x2 fma2(f32x2 a, f32x2 b, f32x2 c) {
    return __builtin_elementwise_fma(a, b, c);
}

// tanh(v) ~= v(10395 + 1260 s + 21 s^2) / (10395 + 4725 s + 210 s^2 + s^3), s=v^2
// max err ~1e-3 over all reals, <4e-4 for |v|<5. One rcp per PAIR via
// 1/(dx*dy): tx = nx*dy*r, ty = ny*dx*r. den >= 10395 -> always finite.
__device__ __forceinline__ f32x2 tanh2(f32x2 v) {
    const f32x2 s = v * v;
    const f32x2 n = v * fma2(s, fma2(s, (f32x2)21.0f, (f32x2)1260.0f), (f32x2)10395.0f);
    const f32x2 d = fma2(s, fma2(s, s + (f32x2)210.0f, (f32x2)4725.0f), (f32x2)10395.0f);
    const float r = __builtin_amdgcn_rcpf(d.x * d.y);
    f32x2 dsw; dsw.x = d.y; dsw.y = d.x;
    return (n * dsw) * (f32x2)r;
}

__device__ __forceinline__ float fast_sigmoid(float v) {
    return __builtin_amdgcn_rcpf(1.0f + __expf(-v));
}

__global__ __launch_bounds__(256) void fused_edge_mlp(
    const float* __restrict__ x,
    const int*   __restrict__ dst,
    const float* __restrict__ W1,
    const float* __restrict__ b1,
    const float* __restrict__ W2,
    const float* __restrict__ b2,
    const float* __restrict__ W3,
    const float* __restrict__ b3,
    float* __restrict__ out)
{
    __shared__ float x_lds[NB * ZONES];       // 32 KB: block's x slice
    __shared__ float buf[2][2][8 * ZONES];    // 8 KB: ping-pong row images

    const int tid  = threadIdx.x;
    const int rg   = blockIdx.x;              // rows rg*8 .. rg*8+7
    const int b0   = blockIdx.y * NB;

    const int boff = tid >> 7;                // 0/1: batch of the pair
    const int t    = tid & 127;               // edge slot within row group
    const int e    = rg * 128 + t;            // global edge id
    const int srow = rg * 8 + (t >> 4);       // output row
    const int dcol = dst[e];                  // output col

    // hoist edge weights (f32x4 vector loads; all 16B-aligned)
    const f32x4 w1q0 = ((const f32x4*)(W1 + e * 8))[0];   // W1[e][0][0..3]
    const f32x4 w1q1 = ((const f32x4*)(W1 + e * 8))[1];   // W1[e][1][0..3]
    const f32x4 b1q  = ((const f32x4*)(b1 + e * 4))[0];
    const f32x4 w2k0 = ((const f32x4*)(W2 + e * 16))[0];
    const f32x4 w2k1 = ((const f32x4*)(W2 + e * 16))[1];
    const f32x4 w2k2 = ((const f32x4*)(W2 + e * 16))[2];
    const f32x4 w2k3 = ((const f32x4*)(W2 + e * 16))[3];
    const f32x4 b2q  = ((const f32x4*)(b2 + e * 4))[0];
    const f32x4 w3q  = ((const f32x4*)(W3 + e * 4))[0];
    const float b3s  = b3[e];

    // stage x[b0 .. b0+63][0..127] into LDS, fully coalesced (8 f32x4/thread)
    const f32x4* xg = (const f32x4*)(x + (size_t)b0 * ZONES);
    f32x4* xl = (f32x4*)x_lds;
    #pragma unroll
    for (int i = 0; i < 8; ++i) xl[tid + 256 * i] = xg[tid + 256 * i];

    // ones-init both parity buffers once (beta slots are batch-invariant)
    f32x4* f4 = (f32x4*)buf;
    const f32x4 ones4 = {1.f, 1.f, 1.f, 1.f};
    #pragma unroll
    for (int i = 0; i < 4; ++i) f4[tid + 256 * i] = ones4;
    __syncthreads();

    f32x4* out4 = (f32x4*)out;

    #pragma unroll 2
    for (int it = 0; it < NB / 2; ++it) {
        const int p  = it & 1;
        const int br = 2 * it + boff;          // batch relative to b0

        const float xs = x_lds[br * ZONES + srow];
        const float xd = x_lds[br * ZONES + dcol];

        // ---- packed tiny MLP 2->4->4->1 ----
        f32x2 xs2; xs2.x = xs; xs2.y = xs;
        f32x2 xd2; xd2.x = xd; xd2.y = xd;

        f32x2 z01 = fma2(xs2, w1q0.xy, fma2(xd2, w1q1.xy, b1q.xy));
        f32x2 z23 = fma2(xs2, w1q0.zw, fma2(xd2, w1q1.zw, b1q.zw));
        const f32x2 h01 = tanh2(z01);
        const f32x2 h23 = tanh2(z23);

        f32x2 hb;
        f32x2 y01 = b2q.xy, y23 = b2q.zw;
        hb.x = h01.x; hb.y = h01.x;
        y01 = fma2(hb, w2k0.xy, y01); y23 = fma2(hb, w2k0.zw, y23);
        hb.x = h01.y; hb.y = h01.y;
        y01 = fma2(hb, w2k1.xy, y01); y23 = fma2(hb, w2k1.zw, y23);
        hb.x = h23.x; hb.y = h23.x;
        y01 = fma2(hb, w2k2.xy, y01); y23 = fma2(hb, w2k2.zw, y23);
        hb.x = h23.y; hb.y = h23.y;
        y01 = fma2(hb, w2k3.xy, y01); y23 = fma2(hb, w2k3.zw, y23);

        const f32x2 g01 = tanh2(y01);
        const f32x2 g23 = tanh2(y23);

        f32x2 acc0; acc0.x = b3s; acc0.y = 0.f;
        const f32x2 acc = fma2(g01, w3q.xy, fma2(g23, w3q.zw, acc0));
        const float beta = fast_sigmoid(acc.x + acc.y);
        // ------------------------------------

        // scatter into parity image (16 distinct cols per row)
        buf[p][boff][(t >> 4) * ZONES + dcol] = beta;
        __syncthreads();

        // coalesced store of both batches' 8 rows (4 KB each)
        #pragma unroll
        for (int bb = 0; bb < 2; ++bb) {
            const int bw = b0 + 2 * it + bb;
            out4[(size_t)bw * (ZONES * ZONES / 4) + rg * 256 + tid] =
                ((f32x4*)buf[p][bb])[tid];
        }
        // no trailing barrier: next iter writes the other parity buffer;
        // this parity is rewritten only after the NEXT iteration's barrier.
    }
}

extern "C" void kernel_launch(void* const* d_in, const int* in_sizes, int n_in,
                              void* d_out, int out_size, void* d_ws, size_t ws_size,
                              hipStream_t stream) {
    // setup_inputs order: x, dtPt, src, dst, W1, b1, W2, b2, W3, b3
    const float* x   = (const float*)d_in[0];
    const int*   dst = (const int*)  d_in[3];
    const float* W1  = (const float*)d_in[4];
    const float* b1  = (const float*)d_in[5];
    const float* W2  = (const float*)d_in[6];
    const float* b2  = (const float*)d_in[7];
    const float* W3  = (const float*)d_in[8];
    const float* b3  = (const float*)d_in[9];
    float* out = (float*)d_out;

    const int B = in_sizes[0] / ZONES;     // 4096
    dim3 grid(ZONES / 8, B / NB);          // (16, 64) = 1024 blocks, 4/CU
    fused_edge_mlp<<<grid, 256, 0, stream>>>(x, dst, W1, b1, W2, b2, W3, b3, out);
}